// Round 8
// baseline (156.772 us; speedup 1.0000x reference)
//
#include <hip/hip_runtime.h>

typedef unsigned short u16;
typedef unsigned int u32;
typedef __attribute__((ext_vector_type(8))) short bf16x8;
typedef __attribute__((ext_vector_type(4))) short bf16x4;
typedef __attribute__((ext_vector_type(4))) float f32x4;

#define MFMA(a, b, c) __builtin_amdgcn_mfma_f32_16x16x32_bf16((a), (b), (c), 0, 0, 0)
#define MFMA16(a, b, c) __builtin_amdgcn_mfma_f32_16x16x16bf16_1k((a), (b), (c), 0, 0, 0)

// round-to-nearest-even f32 -> bf16
static __device__ __forceinline__ u16 f2bf(float x) {
  u32 u = __float_as_uint(x);
  u += 0x7FFFu + ((u >> 16) & 1u);
  return (u16)(u >> 16);
}
// pack two f32 -> (bf16(hi)<<16)|bf16(lo), truncating (hot paths)
static __device__ __forceinline__ u32 packbf_t(float hi, float lo) {
  return __builtin_amdgcn_perm(__float_as_uint(hi), __float_as_uint(lo), 0x07060302u);
}
// rounded pack: lo | hi<<16
static __device__ __forceinline__ u32 packbf(float lo, float hi) {
  return (u32)f2bf(lo) | ((u32)f2bf(hi) << 16);
}
// load 8 consecutive fp32 -> bf16x8 (rounded)
static __device__ __forceinline__ bf16x8 ld8bf(const float* __restrict__ p) {
  const float4 a = *(const float4*)p;
  const float4 b = *(const float4*)(p + 4);
  union { u32 u[4]; bf16x8 v; } r;
  r.u[0] = packbf(a.x, a.y);
  r.u[1] = packbf(a.z, a.w);
  r.u[2] = packbf(b.x, b.y);
  r.u[3] = packbf(b.z, b.w);
  return r.v;
}

// ---------------------------------------------------------------------------
// Kernel 1: FUSED projections + attention. Each block owns (b, br, 64
// queries). Per 64-key chunk, wave w projects its own 16-key K/V slice from
// h/m on the fly (weights pre-converted to register fragments at block
// start), consumes them immediately:
//   - x frags: 16 transposed scalar fp32 loads (A- and B-layout identical)
//   - K-proj: MFMA -> same-wave LDS bounce -> A-frags (no barrier)
//   - V-proj: MFMA C/D output IS the PV MFMA16 A-frag (pure register)
//   - QK^T -> exp -> pack = MFMA16 B-frag (r6-verified zero-transpose PV)
// Single-pass unnormalized softmax; cross-wave key-split combine at end.
// Also emits hbuf (bf16 h^T) from the Q staging loads (br==0 blocks).
// grid 512 = 16 b (XCD-affine) x 2 br x 16 qh; block 256; 2 blocks/CU.
// ---------------------------------------------------------------------------
__global__ __launch_bounds__(256, 2) void fused_attn_kernel(
    const float* __restrict__ h, const float* __restrict__ m_,
    const float* __restrict__ Wq, const float* __restrict__ bq,
    const float* __restrict__ Wk, const float* __restrict__ bk,
    const float* __restrict__ Wk2, const float* __restrict__ bk2,
    const float* __restrict__ Wv, const float* __restrict__ bv,
    const float* __restrict__ Wv2, const float* __restrict__ bv2,
    u16* __restrict__ hbuf, u16* __restrict__ Ztb)
{
  const int id = blockIdx.x;
  const int b = id & 15;            // batch -> fixed XCD (id%8 == b%8)
  const int br = (id >> 4) & 1;
  const int qh = id >> 5;           // 0..15
  const float* __restrict__ X = (br ? m_ : h) + b * 65536;  // (64c, 1024px)
  const float* __restrict__ H = h + b * 65536;
  const float* __restrict__ WK = br ? Wk2 : Wk;
  const float* __restrict__ BK = br ? bk2 : bk;
  const float* __restrict__ WV = br ? Wv2 : Wv;
  const float* __restrict__ BV = br ? bv2 : bv;

  __shared__ __align__(16) u16 Qlds[64 * 72];
  __shared__ __align__(16) u16 Klds[64 * 72];
  __shared__ __align__(16) u16 zcb[4 * 64 * 68];
  __shared__ float rsw[4][64];

  const int tid = threadIdx.x, w = tid >> 6, lane = tid & 63;
  const int mm = lane & 15, q = lane >> 4;
  const int q0 = qh * 64;

  // ---- weight fragments in registers (fp32 -> bf16 inline)
  bf16x8 wqA0[4], wqA1[4], wkA0[4], wkA1[4], wvB0[4], wvB1[4];
#pragma unroll
  for (int ot = 0; ot < 4; ++ot) {
    const int ro = (ot * 16 + mm) * 64;
    wqA0[ot] = ld8bf(Wq + ro + q * 8);
    wqA1[ot] = ld8bf(Wq + ro + 32 + q * 8);
    wkA0[ot] = ld8bf(WK + ro + q * 8);
    wkA1[ot] = ld8bf(WK + ro + 32 + q * 8);
    wvB0[ot] = ld8bf(WV + ro + q * 8);
    wvB1[ot] = ld8bf(WV + ro + 32 + q * 8);
  }
  float4 bkq[4];
  float bvs[4];
#pragma unroll
  for (int ot = 0; ot < 4; ++ot) {
    bkq[ot] = *(const float4*)(BK + ot * 16 + q * 4);
    bvs[ot] = BV[ot * 16 + mm];
  }

  // ---- Q projection for this block's 64 queries (+ hbuf for br==0)
  {
    const int qp = q0 + w * 16 + mm;  // this lane's query pixel
    float xq[16];
#pragma unroll
    for (int i = 0; i < 2; ++i)
#pragma unroll
      for (int j = 0; j < 8; ++j) xq[i * 8 + j] = H[(i * 32 + q * 8 + j) * 1024 + qp];
    union { u32 u[4]; bf16x8 v; } x0, x1;
#pragma unroll
    for (int p = 0; p < 4; ++p) {
      x0.u[p] = packbf(xq[2 * p], xq[2 * p + 1]);
      x1.u[p] = packbf(xq[8 + 2 * p], xq[9 + 2 * p]);
    }
    if (br == 0) {
      u16* hp = hbuf + (b * 1024 + qp) * 64;
      uint4 h0, h1;
      h0.x = x0.u[0]; h0.y = x0.u[1]; h0.z = x0.u[2]; h0.w = x0.u[3];
      h1.x = x1.u[0]; h1.y = x1.u[1]; h1.z = x1.u[2]; h1.w = x1.u[3];
      *(uint4*)(hp + q * 8) = h0;
      *(uint4*)(hp + 32 + q * 8) = h1;
    }
#pragma unroll
    for (int ot = 0; ot < 4; ++ot) {
      const float4 b4 = *(const float4*)(bq + ot * 16 + q * 4);
      f32x4 d = {b4.x, b4.y, b4.z, b4.w};
      d = MFMA(wqA0[ot], x0.v, d);
      d = MFMA(wqA1[ot], x1.v, d);
      uint2 val;
      val.x = packbf(d[0], d[1]);
      val.y = packbf(d[2], d[3]);
      *(uint2*)(Qlds + (w * 16 + mm) * 72 + ot * 16 + q * 4) = val;
    }
  }
  __syncthreads();
  bf16x8 qb0[4], qb1[4];
#pragma unroll
  for (int qt = 0; qt < 4; ++qt) {
    qb0[qt] = *(const bf16x8*)(Qlds + (qt * 16 + mm) * 72 + q * 8);
    qb1[qt] = *(const bf16x8*)(Qlds + (qt * 16 + mm) * 72 + 32 + q * 8);
  }

  f32x4 z[4][4];  // [qt][ct] = Z[c=ct*16+q*4+r][query=qt*16+mm] partial
#pragma unroll
  for (int qt = 0; qt < 4; ++qt)
#pragma unroll
    for (int ct = 0; ct < 4; ++ct) z[qt][ct] = (f32x4){0.f, 0.f, 0.f, 0.f};
  float rp[4] = {0.f, 0.f, 0.f, 0.f};

  // ---- K-loop: project K/V slice + attend, per wave, no barriers
  float xn[16];
  union { u32 u[4]; bf16x8 v; } xb0, xb1;
  auto xload = [&](int kc) {
    const float* Xp = X + kc * 64 + w * 16 + mm;
#pragma unroll
    for (int i = 0; i < 2; ++i)
#pragma unroll
      for (int j = 0; j < 8; ++j) xn[i * 8 + j] = Xp[(i * 32 + q * 8 + j) * 1024];
  };
  auto xpack = [&]() {
#pragma unroll
    for (int p = 0; p < 4; ++p) {
      xb0.u[p] = packbf(xn[2 * p], xn[2 * p + 1]);
      xb1.u[p] = packbf(xn[8 + 2 * p], xn[9 + 2 * p]);
    }
  };

  xload(0);
  xpack();
#pragma unroll 1
  for (int kc = 0; kc < 16; ++kc) {
    if (kc < 15) xload(kc + 1);  // prefetch next x slice

    // K-proj (A=W, B=x): D[col=key=mm][row=d] -> same-wave LDS bounce
#pragma unroll
    for (int ot = 0; ot < 4; ++ot) {
      f32x4 d = {bkq[ot].x, bkq[ot].y, bkq[ot].z, bkq[ot].w};
      d = MFMA(wkA0[ot], xb0.v, d);
      d = MFMA(wkA1[ot], xb1.v, d);
      uint2 val;
      val.x = packbf(d[0], d[1]);
      val.y = packbf(d[2], d[3]);
      *(uint2*)(Klds + (w * 16 + mm) * 72 + ot * 16 + q * 4) = val;
    }
    const bf16x8 kf0 = *(const bf16x8*)(Klds + (w * 16 + mm) * 72 + q * 8);
    const bf16x8 kf1 = *(const bf16x8*)(Klds + (w * 16 + mm) * 72 + 32 + q * 8);

    // V-proj (A=x, B=W): D[col=c][row=key] == PV MFMA16 A-frag, pure register
    bf16x4 vf[4];
#pragma unroll
    for (int ct = 0; ct < 4; ++ct) {
      f32x4 d = {bvs[ct], bvs[ct], bvs[ct], bvs[ct]};
      d = MFMA(xb0.v, wvB0[ct], d);
      d = MFMA(xb1.v, wvB1[ct], d);
      union { u32 u[2]; bf16x4 v; } pv;
      pv.u[0] = packbf_t(d[1], d[0]);
      pv.u[1] = packbf_t(d[3], d[2]);
      vf[ct] = pv.v;
    }

    // attention: S^T = K·Q^T, exp in C/D layout == MFMA16 B-frag
#pragma unroll
    for (int qt = 0; qt < 4; ++qt) {
      f32x4 s = {0.f, 0.f, 0.f, 0.f};
      s = MFMA(kf0, qb0[qt], s);
      s = MFMA(kf1, qb1[qt], s);
      const float e0 = __expf(s[0]), e1 = __expf(s[1]);
      const float e2 = __expf(s[2]), e3 = __expf(s[3]);
      rp[qt] += (e0 + e1) + (e2 + e3);
      union { u32 u[2]; bf16x4 v; } pb;
      pb.u[0] = packbf_t(e1, e0);
      pb.u[1] = packbf_t(e3, e2);
#pragma unroll
      for (int ct = 0; ct < 4; ++ct) z[qt][ct] = MFMA16(vf[ct], pb.v, z[qt][ct]);
    }

    if (kc < 15) xpack();
  }

  // ---- publish partials (zcb is its own LDS, no overlay race)
#pragma unroll
  for (int qt = 0; qt < 4; ++qt) {
    float v = rp[qt];
    v += __shfl_xor(v, 16);
    v += __shfl_xor(v, 32);
    if (q == 0) rsw[w][qt * 16 + mm] = v;
#pragma unroll
    for (int ct = 0; ct < 4; ++ct) {
      uint2 val;
      val.x = packbf_t(z[qt][ct][1], z[qt][ct][0]);
      val.y = packbf_t(z[qt][ct][3], z[qt][ct][2]);
      *(uint2*)(zcb + w * 4352 + (qt * 16 + mm) * 68 + ct * 16 + q * 4) = val;
    }
  }
  __syncthreads();

  // ---- combine 4 key-splits, normalize, store bf16 (B,N,128)
  const int c2 = tid & 31, qr = tid >> 5;
#pragma unroll
  for (int i = 0; i < 8; ++i) {
    const int query = qr + i * 8;
    const float rt = rsw[0][query] + rsw[1][query] + rsw[2][query] + rsw[3][query];
    const float rinv = __builtin_amdgcn_rcpf(rt);
    float vlo = 0.f, vhi = 0.f;
#pragma unroll
    for (int ww = 0; ww < 4; ++ww) {
      const u32 u = *(const u32*)(zcb + ww * 4352 + query * 68 + c2 * 2);
      vlo += __uint_as_float(u << 16);
      vhi += __uint_as_float(u & 0xffff0000u);
    }
    vlo *= rinv;
    vhi *= rinv;
    *(u32*)(Ztb + (b * 1024 + q0 + query) * 128 + br * 64 + c2 * 2) = packbf_t(vhi, vlo);
  }
}

// ---------------------------------------------------------------------------
// Kernel 2: fused zproj (128->128) + final (192->192) + gates, all MFMA.
// Weights converted fp32->bf16 fragments inline (no prep kernel, no
// permuted copies: gate-major row index computed directly).
// grid (16 b, 32 nt): linear%8 == b%8 matches fused_attn's Ztb writers.
// ---------------------------------------------------------------------------
__global__ __launch_bounds__(256) void tail_kernel(
    const u16* __restrict__ Ztb, const u16* __restrict__ hbuf,
    const float* __restrict__ m_, const float* __restrict__ Wz,
    const float* __restrict__ bz, const float* __restrict__ Wm,
    const float* __restrict__ bm, float* __restrict__ out)
{
  const int b = blockIdx.x, n0 = blockIdx.y * 32;
  __shared__ __align__(16) u16 zp[32][136];  // bf16 Zp tile [px][c]
  const int tid = threadIdx.x, lane = tid & 63, wv = tid >> 6;
  const int mm = lane & 15, q = lane >> 4;
  const int pxt = wv & 1, oh = wv >> 1;

  // ---- Phase A: Zp = Wz @ [Zh;Zm] + bz  (A=W: lane rows = contiguous o-ch)
  {
    bf16x8 za[4];
#pragma unroll
    for (int ks = 0; ks < 4; ++ks)
      za[ks] = *(const bf16x8*)(Ztb + (b * 1024 + n0 + pxt * 16 + mm) * 128 +
                                ks * 32 + q * 8);
#pragma unroll
    for (int ot = 0; ot < 4; ++ot) {
      const int o0 = oh * 64 + ot * 16;
      const float4 b4 = *(const float4*)(bz + o0 + q * 4);
      f32x4 d = {b4.x, b4.y, b4.z, b4.w};
#pragma unroll
      for (int ks = 0; ks < 4; ++ks) {
        const bf16x8 wb = ld8bf(Wz + (o0 + mm) * 128 + ks * 32 + q * 8);
        d = MFMA(wb, za[ks], d);
      }
      uint2 val;
      val.x = packbf(d[0], d[1]);
      val.y = packbf(d[2], d[3]);
      *(uint2*)&zp[pxt * 16 + mm][o0 + q * 4] = val;
    }
  }
  __syncthreads();

  // ---- Phase B: combined = Wm @ [Zp; h] + bm (gate-major row o inline)
  {
    const int hb2 = oh;
    bf16x8 fa[6];
#pragma unroll
    for (int ks = 0; ks < 4; ++ks)
      fa[ks] = *(const bf16x8*)&zp[pxt * 16 + mm][ks * 32 + q * 8];
    {
      const u16* hp = hbuf + (b * 1024 + n0 + pxt * 16 + mm) * 64;
      fa[4] = *(const bf16x8*)(hp + q * 8);
      fa[5] = *(const bf16x8*)(hp + 32 + q * 8);
    }
    f32x4 dd[6];
#pragma unroll
    for (int j = 0; j < 6; ++j) {
      const int o = (j % 3) * 64 + (hb2 * 2 + j / 3) * 16 + mm;
      const float bb = bm[o];
      f32x4 d = {bb, bb, bb, bb};
#pragma unroll
      for (int ks = 0; ks < 6; ++ks) {
        const bf16x8 wb = ld8bf(Wm + o * 192 + ks * 32 + q * 8);
        d = MFMA(fa[ks], wb, d);
      }
      dd[j] = d;
    }
#pragma unroll
    for (int ctl = 0; ctl < 2; ++ctl) {
      const int c = (hb2 * 2 + ctl) * 16 + mm;
      const int px = n0 + pxt * 16 + q * 4;
      const float4 mold = *(const float4*)(m_ + (b * 64 + c) * 1024 + px);
      float4 nh, nm;
#pragma unroll
      for (int r = 0; r < 4; ++r) {
        const float xo = dd[0 + ctl * 3 / 3 * 0 + (ctl * 3 + 0)][r];  // dd[ctl*3+0]
        const float xg = dd[ctl * 3 + 1][r];
        const float xi = dd[ctl * 3 + 2][r];
        const float si = __builtin_amdgcn_rcpf(1.f + __expf(-xi));
        const float th = 1.f - 2.f * __builtin_amdgcn_rcpf(__expf(2.f * xg) + 1.f);
        const float so = __builtin_amdgcn_rcpf(1.f + __expf(-xo));
        const float mo = ((const float*)&mold)[r];
        const float nmv = (1.f - si) * mo + si * th;
        ((float*)&nm)[r] = nmv;
        ((float*)&nh)[r] = so * nmv;
      }
      *(float4*)(out + (b * 64 + c) * 1024 + px) = nh;
      *(float4*)(out + 1048576 + (b * 64 + c) * 1024 + px) = nm;
    }
  }
}

// ---------------------------------------------------------------------------
extern "C" void kernel_launch(void* const* d_in, const int* in_sizes, int n_in,
                              void* d_out, int out_size, void* d_ws, size_t ws_size,
                              hipStream_t stream) {
  const float* h   = (const float*)d_in[0];
  const float* m   = (const float*)d_in[1];
  const float* Wq  = (const float*)d_in[2];
  const float* bq  = (const float*)d_in[3];
  const float* Wk  = (const float*)d_in[4];
  const float* bk  = (const float*)d_in[5];
  const float* Wk2 = (const float*)d_in[6];
  const float* bk2 = (const float*)d_in[7];
  const float* Wv  = (const float*)d_in[8];
  const float* bv  = (const float*)d_in[9];
  const float* Wv2 = (const float*)d_in[10];
  const float* bv2 = (const float*)d_in[11];
  const float* Wz  = (const float*)d_in[12];
  const float* bz  = (const float*)d_in[13];
  const float* Wm  = (const float*)d_in[14];
  const float* bm  = (const float*)d_in[15];
  float* out = (float*)d_out;

  char* ws = (char*)d_ws;
  const size_t MB = 1024 * 1024;
  u16* hbuf = (u16*)(ws + 0 * MB);   // (B,N,64) bf16
  u16* Ztb  = (u16*)(ws + 2 * MB);   // (B,N,128) bf16

  fused_attn_kernel<<<512, 256, 0, stream>>>(h, m, Wq, bq, Wk, bk, Wk2, bk2,
                                             Wv, bv, Wv2, bv2, hbuf, Ztb);
  tail_kernel<<<dim3(16, 32), 256, 0, stream>>>(Ztb, hbuf, m, Wz, bz, Wm, bm, out);
}